// Round 8
// baseline (312.238 us; speedup 1.0000x reference)
//
#include <hip/hip_runtime.h>
#include <stdint.h>
#include <stddef.h>

// Problem dims (fixed by reference)
#define BB 8192
#define TT 26
#define VV 23
#define EE 100
#define HH 128
#define LL 64

typedef __attribute__((ext_vector_type(8))) short bf16x8;  // 8 bf16 = 4 VGPRs
typedef __attribute__((ext_vector_type(4))) float f32x4;   // MFMA 16x16 C/D

#define MFMA(a, b, c) __builtin_amdgcn_mfma_f32_16x16x32_bf16((a), (b), (c), 0, 0, 0)

// ---------------- workspace layout (bytes) ----------------
#define OFF_GRUW   0ull                  // GRU Whh B-frags: 24ct*4kc*1024
#define OFF_TBL    98304ull              // one-hot table B-frags: 24ct*1024
#define OFF_LSTMW  122880ull             // LSTM fused W B-frags: 28ct*8kc*1024 (kc0-3=y, kc4-7=h)
#define OFF_OUTW   352256ull             // out_w B-frags: 2ct*4kc*1024
#define OFF_FCZW   360448ull             // fc_z_w B-frags: 8ct*2kc*1024
#define OFF_LBIAS  376832ull             // fused LSTM bias 4*112 fp32

__device__ __forceinline__ void force_frag(bf16x8& v) { asm volatile("" : "+v"(v)); }

// Exact RNE (prep only)
__device__ __forceinline__ unsigned short f2bf(float f) {
  union { float f; unsigned u; } v; v.f = f;
  unsigned u = v.u;
  return (unsigned short)((u + 0x7FFFu + ((u >> 16) & 1u)) >> 16);
}
// Fast in-loop convert (round-half-up)
__device__ __forceinline__ unsigned short f2bf_fast(float f) {
  union { float f; unsigned u; } v; v.f = f;
  return (unsigned short)((v.u + 0x8000u) >> 16);
}
#define LOG2E 1.4426950408889634f
__device__ __forceinline__ float sigm(float x) {
  return __builtin_amdgcn_rcpf(1.0f + __builtin_amdgcn_exp2f(-x * LOG2E));
}
__device__ __forceinline__ float tanh_(float x) {
  return __builtin_fmaf(-2.0f,
      __builtin_amdgcn_rcpf(1.0f + __builtin_amdgcn_exp2f(x * (2.0f * LOG2E))), 1.0f);
}

// =====================================================================
// K0a: one-hot table build, LDS-staged.
// =====================================================================
__global__ __launch_bounds__(512) void prep_table_kernel(
    const float* __restrict__ emb, const float* __restrict__ gru_wih,
    const float* __restrict__ gru_bih, char* __restrict__ ws)
{
  __shared__ float emb_s[VV * EE];
  __shared__ float wih_s[16 * EE];
  __shared__ float bih_s[16];
  const int tid = threadIdx.x;
  const int ct  = blockIdx.x;           // 0..23
  const int n0  = ct * 16;

  for (int i = tid; i < VV * EE; i += 512) emb_s[i] = emb[i];
  for (int i = tid; i < 16 * EE; i += 512) wih_s[i] = gru_wih[n0 * EE + i];
  if (tid < 16) bih_s[tid] = gru_bih[n0 + tid];
  __syncthreads();

  const int j    = tid & 7;
  const int lane = (tid >> 3) & 63;
  const int n16  = lane & 15;
  const int k    = ((lane >> 4) & 3) * 8 + j;
  float v = 0.0f;
  if (k < VV) {
    const float* ep = emb_s + k * EE;
    const float* wp = wih_s + n16 * EE;
    float s0 = 0.f, s1 = 0.f, s2 = 0.f, s3 = 0.f;
#pragma unroll 5
    for (int m = 0; m < EE; m += 4) {
      s0 += ep[m] * wp[m];         s1 += ep[m + 1] * wp[m + 1];
      s2 += ep[m + 2] * wp[m + 2]; s3 += ep[m + 3] * wp[m + 3];
    }
    v = bih_s[n16] + ((s0 + s1) + (s2 + s3));
  }
  *(unsigned short*)(ws + OFF_TBL + (size_t)(ct * 512 + tid) * 2) = f2bf(v);
}

// =====================================================================
// K0b: remaining weight swizzles.
// =====================================================================
__global__ __launch_bounds__(256) void prep_main_kernel(
    const float* __restrict__ fc_z_w, const float* __restrict__ gru_whh,
    const float* __restrict__ lstm_wih, const float* __restrict__ lstm_whh,
    const float* __restrict__ lstm_bih, const float* __restrict__ lstm_bhh,
    const float* __restrict__ out_w, char* __restrict__ ws)
{
  int e = blockIdx.x * 256 + threadIdx.x;

  if (e < 49152) {  // GRU Whh (384x128)
    int j = e & 7, lane = (e >> 3) & 63, kc = (e >> 9) & 3, ct = e >> 11;
    int n = ct * 16 + (lane & 15);
    int k = kc * 32 + ((lane >> 4) & 3) * 8 + j;
    *(unsigned short*)(ws + OFF_GRUW + (size_t)e * 2) = f2bf(gru_whh[n * HH + k]);
    return;
  }
  e -= 49152;
  if (e < 114688) {  // LSTM fused W: row=112g+c, K=[y 0..127 | h 0..127]
    int j = e & 7, lane = (e >> 3) & 63, kc = (e >> 9) & 7, ct = e >> 12;
    int row = ct * 16 + (lane & 15);
    int g = row / 112, c = row % 112;
    int q = (lane >> 4) & 3;
    float v = 0.0f;
    if (c < EE) {
      if (kc < 4) {
        int k = kc * 32 + q * 8 + j;
        v = lstm_wih[(g * EE + c) * HH + k];
      } else {
        int k = (kc - 4) * 32 + q * 8 + j;
        if (k < EE) v = lstm_whh[(g * EE + c) * EE + k];
      }
    }
    *(unsigned short*)(ws + OFF_LSTMW + (size_t)e * 2) = f2bf(v);
    return;
  }
  e -= 114688;
  if (e < 4096) {  // out_w (23x100 -> 32x128)
    int j = e & 7, lane = (e >> 3) & 63, kc = (e >> 9) & 3, ct = e >> 11;
    int n = ct * 16 + (lane & 15);
    int k = kc * 32 + ((lane >> 4) & 3) * 8 + j;
    float v = (n < VV && k < EE) ? out_w[n * EE + k] : 0.0f;
    *(unsigned short*)(ws + OFF_OUTW + (size_t)e * 2) = f2bf(v);
    return;
  }
  e -= 4096;
  if (e < 8192) {  // fc_z_w (128x64)
    int j = e & 7, lane = (e >> 3) & 63, kc = (e >> 9) & 1, ct = e >> 10;
    int n = ct * 16 + (lane & 15);
    int k = kc * 32 + ((lane >> 4) & 3) * 8 + j;
    *(unsigned short*)(ws + OFF_FCZW + (size_t)e * 2) = f2bf(fc_z_w[n * LL + k]);
    return;
  }
  e -= 8192;
  if (e < 448) {  // fused LSTM bias
    int g = e / 112, c = e % 112;
    float v = (c < EE) ? (lstm_bih[g * EE + c] + lstm_bhh[g * EE + c]) : 0.0f;
    *(float*)(ws + OFF_LBIAS + (size_t)e * 4) = v;
  }
}

// =====================================================================
// K1: FUSED gru+lstm+logits pipeline. 512 blocks x 1024 thr (16 waves),
// 16 batch rows/block, end-to-end. Per phase p (28 phases, 1 barrier):
//   waves 0-7  (GRU):    step p      y(p)   -> hfrag[(p+1)&1]
//   waves 8-14 (LSTM):   step p-1    h(p-1) -> lhbuf[p&1]
//   wave 15    (logits): step p-2    -> out
// y/h never touch HBM; heterogeneous roles per SIMD overlap MFMA & VALU.
// =====================================================================
__global__ __launch_bounds__(1024, 4) void fused_kernel(
    const float* __restrict__ z, const int* __restrict__ x_in,
    const float* __restrict__ fc_z_b, const float* __restrict__ gru_bhh,
    const unsigned short* __restrict__ gruw, const unsigned short* __restrict__ tbl,
    const unsigned short* __restrict__ fczw,
    const unsigned short* __restrict__ lstmw, const float* __restrict__ lbias,
    const float* __restrict__ out_b, const unsigned short* __restrict__ outw,
    float* __restrict__ out)
{
  __shared__ unsigned short hfrag[2][2048];   // GRU h (=y), A-frag layout
  __shared__ unsigned short lhbuf[2][2048];   // LSTM h, A-frag layout
  __shared__ unsigned char idx_lds[TT * 16];
  const int tid  = threadIdx.x;
  const int wv   = tid >> 6;        // 0..15
  const int lane = tid & 63;
  const int l15  = lane & 15;
  const int q    = (lane >> 4) & 3;
  const int blk  = blockIdx.x;      // 0..511

  // zero LSTM h state (h(-1) = 0)
  for (int i = tid; i < 2 * 2048; i += 1024)
    ((unsigned short*)lhbuf)[i] = 0;

  if (wv < 8) {
    // ================= GRU role =================
    {
      int rid = wv * 64 + lane;     // 0..511
      for (int i = rid; i < TT * 16; i += 512) {
        int t = i >> 4, r = i & 15;
        idx_lds[i] = (unsigned char)x_in[(blk * 16 + r) * TT + t];
      }
    }
    bf16x8 gw[3][4], tw[3];
#pragma unroll
    for (int g = 0; g < 3; g++) {
      int ct = g * 8 + wv;
#pragma unroll
      for (int kc = 0; kc < 4; kc++) {
        gw[g][kc] = *(const bf16x8*)(gruw + (size_t)(ct * 4 + kc) * 512 + lane * 8);
        force_frag(gw[g][kc]);
      }
      tw[g] = *(const bf16x8*)(tbl + (size_t)ct * 512 + lane * 8);
      force_frag(tw[g]);
    }
    const int col = wv * 16 + l15;
    const float b_r = gru_bhh[0 * HH + col];
    const float b_z = gru_bhh[1 * HH + col];
    const float b_n = gru_bhh[2 * HH + col];
    const int wbase = (col >> 5) * 512 + ((col >> 3) & 3) * 128 + (col & 7);

    // h0 = tanh(z @ fc_z_w^T + fc_z_b)
    float h[4];
    {
      bf16x8 fw0 = *(const bf16x8*)(fczw + (size_t)(wv * 2 + 0) * 512 + lane * 8);
      bf16x8 fw1 = *(const bf16x8*)(fczw + (size_t)(wv * 2 + 1) * 512 + lane * 8);
      const float* zp = z + (size_t)(blk * 16 + l15) * LL + q * 8;
      f32x4 z0 = *(const f32x4*)(zp);
      f32x4 z1 = *(const f32x4*)(zp + 4);
      f32x4 z2 = *(const f32x4*)(zp + 32);
      f32x4 z3 = *(const f32x4*)(zp + 36);
      bf16x8 za0, za1;
#pragma unroll
      for (int j = 0; j < 4; j++) {
        za0[j]     = (short)f2bf(z0[j]);
        za0[4 + j] = (short)f2bf(z1[j]);
        za1[j]     = (short)f2bf(z2[j]);
        za1[4 + j] = (short)f2bf(z3[j]);
      }
      float fzb = fc_z_b[col];
      f32x4 acc = {fzb, fzb, fzb, fzb};
      acc = MFMA(za0, fw0, acc);
      acc = MFMA(za1, fw1, acc);
#pragma unroll
      for (int i = 0; i < 4; i++) {
        h[i] = tanh_(acc[i]);
        hfrag[0][wbase + (q * 4 + i) * 8] = f2bf_fast(h[i]);
      }
    }
    __syncthreads();                              // barrier A

    for (int p = 0; p < TT + 2; p++) {
      if (p < TT) {
        int iv = idx_lds[p * 16 + l15];
        bf16x8 oh;
#pragma unroll
        for (int j = 0; j < 8; j++)
          oh[j] = (short)((iv == q * 8 + j) ? 0x3F80 : 0);

        f32x4 ar  = {b_r, b_r, b_r, b_r};
        f32x4 az  = {b_z, b_z, b_z, b_z};
        f32x4 ahn = {b_n, b_n, b_n, b_n};
        f32x4 axn = {0.0f, 0.0f, 0.0f, 0.0f};
        ar  = MFMA(oh, tw[0], ar);
        az  = MFMA(oh, tw[1], az);
        axn = MFMA(oh, tw[2], axn);

        bf16x8 a[4];
#pragma unroll
        for (int kc = 0; kc < 4; kc++)
          a[kc] = *(const bf16x8*)((const char*)hfrag[p & 1] + kc * 1024 + lane * 16);
#pragma unroll
        for (int kc = 0; kc < 4; kc++) {
          ar  = MFMA(a[kc], gw[0][kc], ar);
          az  = MFMA(a[kc], gw[1][kc], az);
          ahn = MFMA(a[kc], gw[2][kc], ahn);
        }
#pragma unroll
        for (int i = 0; i < 4; i++) {
          float r  = sigm(ar[i]);
          float zg = sigm(az[i]);
          float n  = tanh_(__builtin_fmaf(r, ahn[i], axn[i]));
          h[i] = __builtin_fmaf(zg, h[i] - n, n);
          hfrag[(p + 1) & 1][wbase + (q * 4 + i) * 8] = f2bf_fast(h[i]);
        }
      }
      __syncthreads();
    }
  } else if (wv < 15) {
    // ================= LSTM role =================
    const int tile = wv - 8;        // 0..6
    bf16x8 lw[4][8];
#pragma unroll
    for (int g = 0; g < 4; g++)
#pragma unroll
      for (int kc = 0; kc < 8; kc++) {
        lw[g][kc] = *(const bf16x8*)(lstmw + (size_t)((g * 7 + tile) * 8 + kc) * 512 + lane * 8);
        force_frag(lw[g][kc]);
      }
    const int col = tile * 16 + l15;
    float b[4];
#pragma unroll
    for (int g = 0; g < 4; g++) b[g] = lbias[g * 112 + col];
    const int wbase = (col >> 5) * 512 + ((col >> 3) & 3) * 128 + (col & 7);
    float c[4] = {0, 0, 0, 0};
    __syncthreads();                              // barrier A

    for (int p = 0; p < TT + 2; p++) {
      if (p >= 1 && p <= TT) {
        bf16x8 ya[4], ha[4];
#pragma unroll
        for (int kc = 0; kc < 4; kc++) {
          ya[kc] = *(const bf16x8*)((const char*)hfrag[p & 1] + kc * 1024 + lane * 16);
          ha[kc] = *(const bf16x8*)((const char*)lhbuf[(p - 1) & 1] + kc * 1024 + lane * 16);
        }
        f32x4 ai = {b[0], b[0], b[0], b[0]};
        f32x4 af = {b[1], b[1], b[1], b[1]};
        f32x4 ag = {b[2], b[2], b[2], b[2]};
        f32x4 ao = {b[3], b[3], b[3], b[3]};
#pragma unroll
        for (int kc = 0; kc < 4; kc++) {
          ai = MFMA(ya[kc], lw[0][kc], ai);
          af = MFMA(ya[kc], lw[1][kc], af);
          ag = MFMA(ya[kc], lw[2][kc], ag);
          ao = MFMA(ya[kc], lw[3][kc], ao);
        }
#pragma unroll
        for (int kc = 0; kc < 4; kc++) {
          ai = MFMA(ha[kc], lw[0][kc + 4], ai);
          af = MFMA(ha[kc], lw[1][kc + 4], af);
          ag = MFMA(ha[kc], lw[2][kc + 4], ag);
          ao = MFMA(ha[kc], lw[3][kc + 4], ao);
        }
#pragma unroll
        for (int i = 0; i < 4; i++) {
          float ii = sigm(ai[i]), ff = sigm(af[i]);
          float gg = tanh_(ag[i]), oo = sigm(ao[i]);
          float cn = __builtin_fmaf(ff, c[i], ii * gg);
          c[i] = cn;
          lhbuf[p & 1][wbase + (q * 4 + i) * 8] = f2bf_fast(oo * tanh_(cn));
        }
      }
      __syncthreads();
    }
  } else {
    // ================= logits role =================
    bf16x8 ow[2][4];
#pragma unroll
    for (int ct = 0; ct < 2; ct++)
#pragma unroll
      for (int kc = 0; kc < 4; kc++) {
        ow[ct][kc] = *(const bf16x8*)(outw + (size_t)(ct * 4 + kc) * 512 + lane * 8);
        force_frag(ow[ct][kc]);
      }
    float ob[2];
#pragma unroll
    for (int ct = 0; ct < 2; ct++) {
      int cv = ct * 16 + l15;
      ob[ct] = (cv < VV) ? out_b[cv] : 0.0f;
    }
    __syncthreads();                              // barrier A

    for (int p = 0; p < TT + 2; p++) {
      if (p >= 2) {
        const int t = p - 2;
        bf16x8 ha[4];
#pragma unroll
        for (int kc = 0; kc < 4; kc++)
          ha[kc] = *(const bf16x8*)((const char*)lhbuf[(p - 1) & 1] + kc * 1024 + lane * 16);
#pragma unroll
        for (int ct = 0; ct < 2; ct++) {
          f32x4 acc = {ob[ct], ob[ct], ob[ct], ob[ct]};
#pragma unroll
          for (int kc = 0; kc < 4; kc++)
            acc = MFMA(ha[kc], ow[ct][kc], acc);
          int cv = ct * 16 + l15;
          if (cv < VV) {
#pragma unroll
            for (int i = 0; i < 4; i++) {
              int rowg = blk * 16 + q * 4 + i;
              out[((size_t)rowg * TT + t) * VV + cv] = acc[i];
            }
          }
        }
      }
      __syncthreads();
    }
  }
}

extern "C" void kernel_launch(void* const* d_in, const int* in_sizes, int n_in,
                              void* d_out, int out_size, void* d_ws, size_t ws_size,
                              hipStream_t stream) {
  (void)in_sizes; (void)n_in; (void)out_size; (void)ws_size;
  const float* z        = (const float*)d_in[0];
  const int*   x_in     = (const int*)  d_in[1];
  const float* emb      = (const float*)d_in[2];
  const float* fc_z_w   = (const float*)d_in[3];
  const float* fc_z_b   = (const float*)d_in[4];
  const float* gru_wih  = (const float*)d_in[5];
  const float* gru_whh  = (const float*)d_in[6];
  const float* gru_bih  = (const float*)d_in[7];
  const float* gru_bhh  = (const float*)d_in[8];
  const float* lstm_wih = (const float*)d_in[9];
  const float* lstm_whh = (const float*)d_in[10];
  const float* lstm_bih = (const float*)d_in[11];
  const float* lstm_bhh = (const float*)d_in[12];
  const float* out_w    = (const float*)d_in[13];
  const float* out_b    = (const float*)d_in[14];
  char*  ws  = (char*)d_ws;
  float* out = (float*)d_out;

  const unsigned short* gruw  = (const unsigned short*)(ws + OFF_GRUW);
  const unsigned short* tblp  = (const unsigned short*)(ws + OFF_TBL);
  const unsigned short* lstmw = (const unsigned short*)(ws + OFF_LSTMW);
  const unsigned short* outw  = (const unsigned short*)(ws + OFF_OUTW);
  const unsigned short* fczw  = (const unsigned short*)(ws + OFF_FCZW);
  const float*          lbias = (const float*)(ws + OFF_LBIAS);

  prep_main_kernel<<<690, 256, 0, stream>>>(fc_z_w, gru_whh, lstm_wih, lstm_whh,
                                            lstm_bih, lstm_bhh, out_w, ws);
  prep_table_kernel<<<24, 512, 0, stream>>>(emb, gru_wih, gru_bih, ws);
  fused_kernel<<<512, 1024, 0, stream>>>(z, x_in, fc_z_b, gru_bhh,
                                         gruw, tblp, fczw, lstmw, lbias,
                                         out_b, outw, out);
}

// Round 9
// 185.709 us; speedup vs baseline: 1.6813x; 1.6813x over previous
//
#include <hip/hip_runtime.h>
#include <stdint.h>
#include <stddef.h>

// Problem dims (fixed by reference)
#define BB 8192
#define TT 26
#define VV 23
#define EE 100
#define HH 128
#define LL 64

typedef __attribute__((ext_vector_type(8))) short bf16x8;  // 8 bf16 = 4 VGPRs
typedef __attribute__((ext_vector_type(4))) float f32x4;   // MFMA 16x16 C/D

#define MFMA(a, b, c) __builtin_amdgcn_mfma_f32_16x16x32_bf16((a), (b), (c), 0, 0, 0)

// ---------------- workspace layout (bytes) ----------------
#define OFF_GRUW   0ull                  // GRU Whh B-frags: 24ct*4kc*1024
#define OFF_TBL    98304ull              // one-hot table B-frags: 24ct*1024
#define OFF_LSTMW  122880ull             // LSTM fused W B-frags: 28ct*8kc*1024 (kc0-3=y, kc4-7=h)
#define OFF_OUTW   352256ull             // out_w B-frags: 2ct*4kc*1024
#define OFF_FCZW   360448ull             // fc_z_w B-frags: 8ct*2kc*1024
#define OFF_LBIAS  376832ull             // fused LSTM bias 4*112 fp32

// Dynamic-LDS partition (bytes)
#define L_LW    0              // LSTM h-half weight frags: 112 KB (28 ct * 4 kc * 1024)
#define L_HF    114688         // GRU y/h dbuf: 2 * 4096
#define L_LH    122880         // LSTM h dbuf: 2 * 4096
#define L_IDX   131072         // token idx: TT*16
#define L_TOTAL 131520

__device__ __forceinline__ void force_frag(bf16x8& v) { asm volatile("" : "+v"(v)); }

// Exact RNE (prep only)
__device__ __forceinline__ unsigned short f2bf(float f) {
  union { float f; unsigned u; } v; v.f = f;
  unsigned u = v.u;
  return (unsigned short)((u + 0x7FFFu + ((u >> 16) & 1u)) >> 16);
}
// Fast in-loop convert (round-half-up)
__device__ __forceinline__ unsigned short f2bf_fast(float f) {
  union { float f; unsigned u; } v; v.f = f;
  return (unsigned short)((v.u + 0x8000u) >> 16);
}
#define LOG2E 1.4426950408889634f
__device__ __forceinline__ float sigm(float x) {
  return __builtin_amdgcn_rcpf(1.0f + __builtin_amdgcn_exp2f(-x * LOG2E));
}
__device__ __forceinline__ float tanh_(float x) {
  return __builtin_fmaf(-2.0f,
      __builtin_amdgcn_rcpf(1.0f + __builtin_amdgcn_exp2f(x * (2.0f * LOG2E))), 1.0f);
}

// =====================================================================
// K0a: one-hot table build, LDS-staged.
// =====================================================================
__global__ __launch_bounds__(512) void prep_table_kernel(
    const float* __restrict__ emb, const float* __restrict__ gru_wih,
    const float* __restrict__ gru_bih, char* __restrict__ ws)
{
  __shared__ float emb_s[VV * EE];
  __shared__ float wih_s[16 * EE];
  __shared__ float bih_s[16];
  const int tid = threadIdx.x;
  const int ct  = blockIdx.x;           // 0..23
  const int n0  = ct * 16;

  for (int i = tid; i < VV * EE; i += 512) emb_s[i] = emb[i];
  for (int i = tid; i < 16 * EE; i += 512) wih_s[i] = gru_wih[n0 * EE + i];
  if (tid < 16) bih_s[tid] = gru_bih[n0 + tid];
  __syncthreads();

  const int j    = tid & 7;
  const int lane = (tid >> 3) & 63;
  const int n16  = lane & 15;
  const int k    = ((lane >> 4) & 3) * 8 + j;
  float v = 0.0f;
  if (k < VV) {
    const float* ep = emb_s + k * EE;
    const float* wp = wih_s + n16 * EE;
    float s0 = 0.f, s1 = 0.f, s2 = 0.f, s3 = 0.f;
#pragma unroll 5
    for (int m = 0; m < EE; m += 4) {
      s0 += ep[m] * wp[m];         s1 += ep[m + 1] * wp[m + 1];
      s2 += ep[m + 2] * wp[m + 2]; s3 += ep[m + 3] * wp[m + 3];
    }
    v = bih_s[n16] + ((s0 + s1) + (s2 + s3));
  }
  *(unsigned short*)(ws + OFF_TBL + (size_t)(ct * 512 + tid) * 2) = f2bf(v);
}

// =====================================================================
// K0b: remaining weight swizzles.
// =====================================================================
__global__ __launch_bounds__(256) void prep_main_kernel(
    const float* __restrict__ fc_z_w, const float* __restrict__ gru_whh,
    const float* __restrict__ lstm_wih, const float* __restrict__ lstm_whh,
    const float* __restrict__ lstm_bih, const float* __restrict__ lstm_bhh,
    const float* __restrict__ out_w, char* __restrict__ ws)
{
  int e = blockIdx.x * 256 + threadIdx.x;

  if (e < 49152) {  // GRU Whh (384x128)
    int j = e & 7, lane = (e >> 3) & 63, kc = (e >> 9) & 3, ct = e >> 11;
    int n = ct * 16 + (lane & 15);
    int k = kc * 32 + ((lane >> 4) & 3) * 8 + j;
    *(unsigned short*)(ws + OFF_GRUW + (size_t)e * 2) = f2bf(gru_whh[n * HH + k]);
    return;
  }
  e -= 49152;
  if (e < 114688) {  // LSTM fused W: row=112g+c, K=[y 0..127 | h 0..127]
    int j = e & 7, lane = (e >> 3) & 63, kc = (e >> 9) & 7, ct = e >> 12;
    int row = ct * 16 + (lane & 15);
    int g = row / 112, c = row % 112;
    int q = (lane >> 4) & 3;
    float v = 0.0f;
    if (c < EE) {
      if (kc < 4) {
        int k = kc * 32 + q * 8 + j;
        v = lstm_wih[(g * EE + c) * HH + k];
      } else {
        int k = (kc - 4) * 32 + q * 8 + j;
        if (k < EE) v = lstm_whh[(g * EE + c) * EE + k];
      }
    }
    *(unsigned short*)(ws + OFF_LSTMW + (size_t)e * 2) = f2bf(v);
    return;
  }
  e -= 114688;
  if (e < 4096) {  // out_w (23x100 -> 32x128)
    int j = e & 7, lane = (e >> 3) & 63, kc = (e >> 9) & 3, ct = e >> 11;
    int n = ct * 16 + (lane & 15);
    int k = kc * 32 + ((lane >> 4) & 3) * 8 + j;
    float v = (n < VV && k < EE) ? out_w[n * EE + k] : 0.0f;
    *(unsigned short*)(ws + OFF_OUTW + (size_t)e * 2) = f2bf(v);
    return;
  }
  e -= 4096;
  if (e < 8192) {  // fc_z_w (128x64)
    int j = e & 7, lane = (e >> 3) & 63, kc = (e >> 9) & 1, ct = e >> 10;
    int n = ct * 16 + (lane & 15);
    int k = kc * 32 + ((lane >> 4) & 3) * 8 + j;
    *(unsigned short*)(ws + OFF_FCZW + (size_t)e * 2) = f2bf(fc_z_w[n * LL + k]);
    return;
  }
  e -= 8192;
  if (e < 448) {  // fused LSTM bias
    int g = e / 112, c = e % 112;
    float v = (c < EE) ? (lstm_bih[g * EE + c] + lstm_bhh[g * EE + c]) : 0.0f;
    *(float*)(ws + OFF_LBIAS + (size_t)e * 4) = v;
  }
}

// =====================================================================
// K1: FUSED gru+lstm+logits. 512 blocks x 1024 thr (16 waves), 16 rows.
// R8 failed on registers (16 waves => 128 reg/wave cap; LSTM needed 178
// => scratch spills, WRITE_SIZE 80MB). Fix: LSTM h-half weights (112 KB)
// live in dynamic LDS as B-frags, streamed per phase; every role now
// fits <=128 regs. LDS/block = 128.5 KB (1 block/CU, by design).
//   waves 0-7  (GRU):    step p      y(p)   -> hfrag[(p+1)&1]
//   waves 8-14 (LSTM):   step p-1    h(p-1) -> lhbuf[p&1]
//   wave 15    (logits): step p-2    -> out
// =====================================================================
__global__ __launch_bounds__(1024, 4) void fused_kernel(
    const float* __restrict__ z, const int* __restrict__ x_in,
    const float* __restrict__ fc_z_b, const float* __restrict__ gru_bhh,
    const unsigned short* __restrict__ gruw, const unsigned short* __restrict__ tbl,
    const unsigned short* __restrict__ fczw,
    const unsigned short* __restrict__ lstmw, const float* __restrict__ lbias,
    const float* __restrict__ out_b, const unsigned short* __restrict__ outw,
    float* __restrict__ out)
{
  extern __shared__ char smem[];
  unsigned short* lwlds = (unsigned short*)(smem + L_LW);   // h-half weight frags
  char*           hfrag = smem + L_HF;                      // [buf]*4096 B
  char*           lhbuf = smem + L_LH;                      // [buf]*4096 B
  unsigned char*  idx_lds = (unsigned char*)(smem + L_IDX);

  const int tid  = threadIdx.x;
  const int wv   = tid >> 6;        // 0..15
  const int lane = tid & 63;
  const int l15  = lane & 15;
  const int q    = (lane >> 4) & 3;
  const int blk  = blockIdx.x;      // 0..511

  // cooperative: zero LSTM h state + stage h-half weight frags into LDS
  for (int i = tid; i < 4096; i += 1024)
    ((unsigned short*)lhbuf)[i] = 0;
  for (int f = tid; f < 7168; f += 1024) {          // 7168 b128 chunks = 112 KB
    int frag_i = f >> 6, within = f & 63;
    int ct = frag_i >> 2, kcl = frag_i & 3;
    *(bf16x8*)((char*)lwlds + (size_t)frag_i * 1024 + within * 16) =
        *(const bf16x8*)(lstmw + ((size_t)(ct * 8 + 4 + kcl)) * 512 + within * 8);
  }

  if (wv < 8) {
    // ================= GRU role =================
    {
      int rid = wv * 64 + lane;     // 0..511
      for (int i = rid; i < TT * 16; i += 512) {
        int t = i >> 4, r = i & 15;
        idx_lds[i] = (unsigned char)x_in[(blk * 16 + r) * TT + t];
      }
    }
    bf16x8 gw[3][4], tw[3];
#pragma unroll
    for (int g = 0; g < 3; g++) {
      int ct = g * 8 + wv;
#pragma unroll
      for (int kc = 0; kc < 4; kc++) {
        gw[g][kc] = *(const bf16x8*)(gruw + (size_t)(ct * 4 + kc) * 512 + lane * 8);
        force_frag(gw[g][kc]);
      }
      tw[g] = *(const bf16x8*)(tbl + (size_t)ct * 512 + lane * 8);
      force_frag(tw[g]);
    }
    const int col = wv * 16 + l15;
    const float b_r = gru_bhh[0 * HH + col];
    const float b_z = gru_bhh[1 * HH + col];
    const float b_n = gru_bhh[2 * HH + col];
    const int wbase = (col >> 5) * 512 + ((col >> 3) & 3) * 128 + (col & 7);

    // h0 = tanh(z @ fc_z_w^T + fc_z_b)
    float h[4];
    {
      bf16x8 fw0 = *(const bf16x8*)(fczw + (size_t)(wv * 2 + 0) * 512 + lane * 8);
      bf16x8 fw1 = *(const bf16x8*)(fczw + (size_t)(wv * 2 + 1) * 512 + lane * 8);
      const float* zp = z + (size_t)(blk * 16 + l15) * LL + q * 8;
      f32x4 z0 = *(const f32x4*)(zp);
      f32x4 z1 = *(const f32x4*)(zp + 4);
      f32x4 z2 = *(const f32x4*)(zp + 32);
      f32x4 z3 = *(const f32x4*)(zp + 36);
      bf16x8 za0, za1;
#pragma unroll
      for (int j = 0; j < 4; j++) {
        za0[j]     = (short)f2bf(z0[j]);
        za0[4 + j] = (short)f2bf(z1[j]);
        za1[j]     = (short)f2bf(z2[j]);
        za1[4 + j] = (short)f2bf(z3[j]);
      }
      float fzb = fc_z_b[col];
      f32x4 acc = {fzb, fzb, fzb, fzb};
      acc = MFMA(za0, fw0, acc);
      acc = MFMA(za1, fw1, acc);
#pragma unroll
      for (int i = 0; i < 4; i++) {
        h[i] = tanh_(acc[i]);
        ((unsigned short*)hfrag)[wbase + (q * 4 + i) * 8] = f2bf_fast(h[i]);
      }
    }
    __syncthreads();                              // barrier A

    for (int p = 0; p < TT + 2; p++) {
      if (p < TT) {
        int iv = idx_lds[p * 16 + l15];
        bf16x8 oh;
#pragma unroll
        for (int j = 0; j < 8; j++)
          oh[j] = (short)((iv == q * 8 + j) ? 0x3F80 : 0);

        f32x4 ar  = {b_r, b_r, b_r, b_r};
        f32x4 az  = {b_z, b_z, b_z, b_z};
        f32x4 ahn = {b_n, b_n, b_n, b_n};
        f32x4 axn = {0.0f, 0.0f, 0.0f, 0.0f};
        ar  = MFMA(oh, tw[0], ar);
        az  = MFMA(oh, tw[1], az);
        axn = MFMA(oh, tw[2], axn);

        bf16x8 a[4];
#pragma unroll
        for (int kc = 0; kc < 4; kc++)
          a[kc] = *(const bf16x8*)(hfrag + (p & 1) * 4096 + kc * 1024 + lane * 16);
#pragma unroll
        for (int kc = 0; kc < 4; kc++) {
          ar  = MFMA(a[kc], gw[0][kc], ar);
          az  = MFMA(a[kc], gw[1][kc], az);
          ahn = MFMA(a[kc], gw[2][kc], ahn);
        }
#pragma unroll
        for (int i = 0; i < 4; i++) {
          float r  = sigm(ar[i]);
          float zg = sigm(az[i]);
          float n  = tanh_(__builtin_fmaf(r, ahn[i], axn[i]));
          h[i] = __builtin_fmaf(zg, h[i] - n, n);
          ((unsigned short*)(hfrag + ((p + 1) & 1) * 4096))[wbase + (q * 4 + i) * 8]
              = f2bf_fast(h[i]);
        }
      }
      __syncthreads();
    }
  } else if (wv < 15) {
    // ================= LSTM role =================
    const int tile = wv - 8;        // 0..6
    // y-half weights in registers (64 regs)
    bf16x8 lwy[4][4];
#pragma unroll
    for (int g = 0; g < 4; g++)
#pragma unroll
      for (int kc = 0; kc < 4; kc++) {
        lwy[g][kc] = *(const bf16x8*)(lstmw + (size_t)((g * 7 + tile) * 8 + kc) * 512 + lane * 8);
        force_frag(lwy[g][kc]);
      }
    const int col = tile * 16 + l15;
    float b[4];
#pragma unroll
    for (int g = 0; g < 4; g++) b[g] = lbias[g * 112 + col];
    const int wbase = (col >> 5) * 512 + ((col >> 3) & 3) * 128 + (col & 7);
    float c[4] = {0, 0, 0, 0};
    __syncthreads();                              // barrier A

    for (int p = 0; p < TT + 2; p++) {
      if (p >= 1 && p <= TT) {
        f32x4 ai = {b[0], b[0], b[0], b[0]};
        f32x4 af = {b[1], b[1], b[1], b[1]};
        f32x4 ag = {b[2], b[2], b[2], b[2]};
        f32x4 ao = {b[3], b[3], b[3], b[3]};
        // y-half: reg weights
#pragma unroll
        for (int kc = 0; kc < 4; kc++) {
          bf16x8 ya = *(const bf16x8*)(hfrag + (p & 1) * 4096 + kc * 1024 + lane * 16);
          ai = MFMA(ya, lwy[0][kc], ai);
          af = MFMA(ya, lwy[1][kc], af);
          ag = MFMA(ya, lwy[2][kc], ag);
          ao = MFMA(ya, lwy[3][kc], ao);
        }
        // h-half: LDS-streamed weights (per-kc: 1 ha frag + 4 weight frags)
#pragma unroll
        for (int kc = 0; kc < 4; kc++) {
          bf16x8 ha = *(const bf16x8*)(lhbuf + ((p - 1) & 1) * 4096 + kc * 1024 + lane * 16);
          const char* wb = (const char*)lwlds + (size_t)(tile * 4 + kc) * 1024 + lane * 16;
          bf16x8 w0 = *(const bf16x8*)(wb);
          bf16x8 w1 = *(const bf16x8*)(wb + 28672);       // gate stride 7*4*1024
          bf16x8 w2 = *(const bf16x8*)(wb + 2 * 28672);
          bf16x8 w3 = *(const bf16x8*)(wb + 3 * 28672);
          ai = MFMA(ha, w0, ai);
          af = MFMA(ha, w1, af);
          ag = MFMA(ha, w2, ag);
          ao = MFMA(ha, w3, ao);
        }
#pragma unroll
        for (int i = 0; i < 4; i++) {
          float ii = sigm(ai[i]), ff = sigm(af[i]);
          float gg = tanh_(ag[i]), oo = sigm(ao[i]);
          float cn = __builtin_fmaf(ff, c[i], ii * gg);
          c[i] = cn;
          ((unsigned short*)(lhbuf + (p & 1) * 4096))[wbase + (q * 4 + i) * 8]
              = f2bf_fast(oo * tanh_(cn));
        }
      }
      __syncthreads();
    }
  } else {
    // ================= logits role =================
    bf16x8 ow[2][4];
#pragma unroll
    for (int ct = 0; ct < 2; ct++)
#pragma unroll
      for (int kc = 0; kc < 4; kc++) {
        ow[ct][kc] = *(const bf16x8*)(outw + (size_t)(ct * 4 + kc) * 512 + lane * 8);
        force_frag(ow[ct][kc]);
      }
    float ob[2];
#pragma unroll
    for (int ct = 0; ct < 2; ct++) {
      int cv = ct * 16 + l15;
      ob[ct] = (cv < VV) ? out_b[cv] : 0.0f;
    }
    __syncthreads();                              // barrier A

    for (int p = 0; p < TT + 2; p++) {
      if (p >= 2) {
        const int t = p - 2;
        bf16x8 ha[4];
#pragma unroll
        for (int kc = 0; kc < 4; kc++)
          ha[kc] = *(const bf16x8*)(lhbuf + ((p - 1) & 1) * 4096 + kc * 1024 + lane * 16);
#pragma unroll
        for (int ct = 0; ct < 2; ct++) {
          f32x4 acc = {ob[ct], ob[ct], ob[ct], ob[ct]};
#pragma unroll
          for (int kc = 0; kc < 4; kc++)
            acc = MFMA(ha[kc], ow[ct][kc], acc);
          int cv = ct * 16 + l15;
          if (cv < VV) {
#pragma unroll
            for (int i = 0; i < 4; i++) {
              int rowg = blk * 16 + q * 4 + i;
              out[((size_t)rowg * TT + t) * VV + cv] = acc[i];
            }
          }
        }
      }
      __syncthreads();
    }
  }
}

extern "C" void kernel_launch(void* const* d_in, const int* in_sizes, int n_in,
                              void* d_out, int out_size, void* d_ws, size_t ws_size,
                              hipStream_t stream) {
  (void)in_sizes; (void)n_in; (void)out_size; (void)ws_size;
  const float* z        = (const float*)d_in[0];
  const int*   x_in     = (const int*)  d_in[1];
  const float* emb      = (const float*)d_in[2];
  const float* fc_z_w   = (const float*)d_in[3];
  const float* fc_z_b   = (const float*)d_in[4];
  const float* gru_wih  = (const float*)d_in[5];
  const float* gru_whh  = (const float*)d_in[6];
  const float* gru_bih  = (const float*)d_in[7];
  const float* gru_bhh  = (const float*)d_in[8];
  const float* lstm_wih = (const float*)d_in[9];
  const float* lstm_whh = (const float*)d_in[10];
  const float* lstm_bih = (const float*)d_in[11];
  const float* lstm_bhh = (const float*)d_in[12];
  const float* out_w    = (const float*)d_in[13];
  const float* out_b    = (const float*)d_in[14];
  char*  ws  = (char*)d_ws;
  float* out = (float*)d_out;

  const unsigned short* gruw  = (const unsigned short*)(ws + OFF_GRUW);
  const unsigned short* tblp  = (const unsigned short*)(ws + OFF_TBL);
  const unsigned short* lstmw = (const unsigned short*)(ws + OFF_LSTMW);
  const unsigned short* outw  = (const unsigned short*)(ws + OFF_OUTW);
  const unsigned short* fczw  = (const unsigned short*)(ws + OFF_FCZW);
  const float*          lbias = (const float*)(ws + OFF_LBIAS);

  // allow >64 KB dynamic LDS (idempotent; not a stream op, capture-safe)
  static int lds_attr_set = 0;
  (void)lds_attr_set;
  hipFuncSetAttribute((const void*)fused_kernel,
                      hipFuncAttributeMaxDynamicSharedMemorySize, L_TOTAL);

  prep_main_kernel<<<690, 256, 0, stream>>>(fc_z_w, gru_whh, lstm_wih, lstm_whh,
                                            lstm_bih, lstm_bhh, out_w, ws);
  prep_table_kernel<<<24, 512, 0, stream>>>(emb, gru_wih, gru_bih, ws);
  fused_kernel<<<512, 1024, L_TOTAL, stream>>>(z, x_in, fc_z_b, gru_bhh,
                                               gruw, tblp, fczw, lstmw, lbias,
                                               out_b, outw, out);
}